// Round 1
// baseline (231.954 us; speedup 1.0000x reference)
//
#include <hip/hip_runtime.h>
#include <cstdint>
#include <cstddef>

#define BB 512
#define NEn 100000
#define NRr 400
#define AA 256
#define ENTd 200
#define RELd 200
#define HISTd 400
#define ADIMd 400

__device__ __forceinline__ float dot4(const float4 a, const float4 b) {
  return a.x * b.x + a.y * b.y + a.z * b.z + a.w * b.w;
}
__device__ __forceinline__ float wave_rmax(float v) {
#pragma unroll
  for (int off = 32; off > 0; off >>= 1) v = fmaxf(v, __shfl_xor(v, off));
  return v;
}
__device__ __forceinline__ float wave_rsum(float v) {
#pragma unroll
  for (int off = 32; off > 0; off >>= 1) v += __shfl_xor(v, off);
  return v;
}

// ---------------------------------------------------------------------------
// prep: block 0 -> rel_sum -> alpha_base ; blocks 1..50 -> relation_K (8 rows)
// ---------------------------------------------------------------------------
__global__ __launch_bounds__(256) void prep_kernel(
    const float* __restrict__ rel_emb, const float* __restrict__ W4,
    const float* __restrict__ b4, const float* __restrict__ W5,
    const float* __restrict__ b5, float* __restrict__ RK,
    float* __restrict__ alpha_base) {
  int t = threadIdx.x;
  if (blockIdx.x == 0) {
    __shared__ float rs[RELd];
    if (t < RELd) {
      float s = 0.f;
      for (int r = 0; r < NRr; ++r) s += rel_emb[(size_t)r * RELd + t];
      rs[t] = s;
    }
    __syncthreads();
    if (t < RELd) {
      float acc = b5[t];
      const float4* w = (const float4*)(W5 + (size_t)t * (RELd + ENTd));
      const float4* rv = (const float4*)rs;
      for (int k = 0; k < RELd / 4; ++k) acc += dot4(w[k], rv[k]);
      alpha_base[t] = acc;
    }
  } else {
    int r0 = (blockIdx.x - 1) * 8;
    __shared__ float re[8][RELd];
    for (int i = t; i < 8 * RELd; i += 256)
      re[i / RELd][i % RELd] = rel_emb[(size_t)(r0 + i / RELd) * RELd + i % RELd];
    __syncthreads();
    if (t < RELd) {
      float bv = b4[t];
      float acc[8];
#pragma unroll
      for (int s = 0; s < 8; ++s) acc[s] = bv;
      const float4* w = (const float4*)(W4 + (size_t)t * RELd);
      for (int k = 0; k < RELd / 4; ++k) {
        float4 wv = w[k];
#pragma unroll
        for (int s = 0; s < 8; ++s) acc[s] += dot4(wv, ((const float4*)re[s])[k]);
      }
#pragma unroll
      for (int s = 0; s < 8; ++s) RK[(size_t)(r0 + s) * RELd + t] = acc[s];
    }
  }
}

// ---------------------------------------------------------------------------
// x1: X = relu(W1 . cat(E,H,Q) + b1)   tile: 4 batch rows x 200 outputs
// grid (128, 2)
// ---------------------------------------------------------------------------
__global__ __launch_bounds__(256) void x1_kernel(
    const float* __restrict__ ent_emb, const float* __restrict__ rel_emb,
    const float* __restrict__ H, const int* __restrict__ e_idx,
    const int* __restrict__ q_idx, const float* __restrict__ W1,
    const float* __restrict__ b1, float* __restrict__ X) {
  int b0 = blockIdx.x * 4;
  int t = threadIdx.x;
  __shared__ float cv[4][ENTd + HISTd + RELd];  // [4][800]
  for (int i = t; i < 4 * 800; i += 256) {
    int s = i / 800, k = i % 800;
    float v;
    if (k < ENTd)
      v = ent_emb[(size_t)e_idx[b0 + s] * ENTd + k];
    else if (k < ENTd + HISTd)
      v = H[(size_t)(b0 + s) * HISTd + (k - ENTd)];
    else
      v = rel_emb[(size_t)q_idx[b0 + s] * RELd + (k - ENTd - HISTd)];
    cv[s][k] = v;
  }
  __syncthreads();
  if (t < 200) {
    int j = blockIdx.y * 200 + t;
    float bv = b1[j];
    float acc[4] = {bv, bv, bv, bv};
    const float4* w = (const float4*)(W1 + (size_t)j * 800);
    for (int k = 0; k < 200; ++k) {
      float4 wv = w[k];
#pragma unroll
      for (int s = 0; s < 4; ++s) acc[s] += dot4(wv, ((const float4*)cv[s])[k]);
    }
#pragma unroll
    for (int s = 0; s < 4; ++s)
      X[(size_t)(b0 + s) * ADIMd + j] = fmaxf(acc[s], 0.f);
  }
}

// ---------------------------------------------------------------------------
// x2: X2 = W2 . X + b2   grid (128, 2)
// ---------------------------------------------------------------------------
__global__ __launch_bounds__(256) void x2_kernel(
    const float* __restrict__ X, const float* __restrict__ W2,
    const float* __restrict__ b2, float* __restrict__ X2) {
  int b0 = blockIdx.x * 4;
  int t = threadIdx.x;
  __shared__ float cv[4][ADIMd];
  for (int i = t; i < 4 * ADIMd; i += 256)
    cv[i / ADIMd][i % ADIMd] = X[(size_t)b0 * ADIMd + i];
  __syncthreads();
  if (t < 200) {
    int j = blockIdx.y * 200 + t;
    float bv = b2[j];
    float acc[4] = {bv, bv, bv, bv};
    const float4* w = (const float4*)(W2 + (size_t)j * ADIMd);
    for (int k = 0; k < ADIMd / 4; ++k) {
      float4 wv = w[k];
#pragma unroll
      for (int s = 0; s < 4; ++s) acc[s] += dot4(wv, ((const float4*)cv[s])[k]);
    }
#pragma unroll
    for (int s = 0; s < 4; ++s) X2[(size_t)(b0 + s) * ADIMd + j] = acc[s];
  }
}

// ---------------------------------------------------------------------------
// pred_path: pi = W3.pe+b3 ; la = pi.RK^T ; softmax(la) ; beta = p.rel_emb ;
// alpha = alpha_base + W5r.(400*pe) ; V_A = W6.cat(alpha,beta)+b6
// 4 batch rows per block, grid 128
// ---------------------------------------------------------------------------
__global__ __launch_bounds__(256) void pred_path_kernel(
    const float* __restrict__ ent_emb, const float* __restrict__ rel_emb,
    const int* __restrict__ pred_id, const float* __restrict__ W3,
    const float* __restrict__ b3, const float* __restrict__ W5,
    const float* __restrict__ alpha_base, const float* __restrict__ W6,
    const float* __restrict__ b6, const float* __restrict__ RK,
    float* __restrict__ V_A) {
  int b0 = blockIdx.x * 4;
  int t = threadIdx.x;
  __shared__ float pe[4][ENTd];
  __shared__ float pi[4][RELd];
  __shared__ float la[4][NRr];
  __shared__ float al[4][RELd];
  __shared__ float be[4][RELd];
  for (int i = t; i < 4 * ENTd; i += 256) {
    int s = i / ENTd, k = i % ENTd;
    pe[s][k] = ent_emb[(size_t)pred_id[b0 + s] * ENTd + k];
  }
  __syncthreads();
  if (t < RELd) {
    float bv = b3[t];
    float acc[4] = {bv, bv, bv, bv};
    const float4* w = (const float4*)(W3 + (size_t)t * ENTd);
    for (int k = 0; k < ENTd / 4; ++k) {
      float4 wv = w[k];
#pragma unroll
      for (int s = 0; s < 4; ++s) acc[s] += dot4(wv, ((const float4*)pe[s])[k]);
    }
#pragma unroll
    for (int s = 0; s < 4; ++s) pi[s][t] = acc[s];
  }
  __syncthreads();
  for (int r = t; r < NRr; r += 256) {
    float acc[4] = {0.f, 0.f, 0.f, 0.f};
    const float4* rk = (const float4*)(RK + (size_t)r * RELd);
    for (int k = 0; k < RELd / 4; ++k) {
      float4 rv = rk[k];
#pragma unroll
      for (int s = 0; s < 4; ++s) acc[s] += dot4(rv, ((const float4*)pi[s])[k]);
    }
#pragma unroll
    for (int s = 0; s < 4; ++s) la[s][r] = acc[s];
  }
  __syncthreads();
  {
    // wave w handles sub-batch w's softmax over 400
    int w = t >> 6, lane = t & 63;
    float m = -INFINITY;
    for (int r = lane; r < NRr; r += 64) m = fmaxf(m, la[w][r]);
    m = wave_rmax(m);
    float sum = 0.f;
    for (int r = lane; r < NRr; r += 64) {
      float e = expf(la[w][r] - m);
      la[w][r] = e;
      sum += e;
    }
    sum = wave_rsum(sum);
    float inv = 1.f / sum;
    for (int r = lane; r < NRr; r += 64) la[w][r] *= inv;
  }
  __syncthreads();
  if (t < RELd) {
    // beta = p . rel_emb
    float acc[4] = {0.f, 0.f, 0.f, 0.f};
    for (int r = 0; r < NRr; ++r) {
      float rv = rel_emb[(size_t)r * RELd + t];
#pragma unroll
      for (int s = 0; s < 4; ++s) acc[s] += rv * la[s][r];
    }
#pragma unroll
    for (int s = 0; s < 4; ++s) be[s][t] = acc[s];
    // alpha = alpha_base + W5[:,200:] . (400 * pe)
    float ab = alpha_base[t];
    float acc2[4] = {ab, ab, ab, ab};
    const float4* w5 = (const float4*)(W5 + (size_t)t * (RELd + ENTd) + RELd);
    for (int k = 0; k < ENTd / 4; ++k) {
      float4 wv = w5[k];
      wv.x *= 400.f; wv.y *= 400.f; wv.z *= 400.f; wv.w *= 400.f;
#pragma unroll
      for (int s = 0; s < 4; ++s) acc2[s] += dot4(wv, ((const float4*)pe[s])[k]);
    }
#pragma unroll
    for (int s = 0; s < 4; ++s) al[s][t] = acc2[s];
  }
  __syncthreads();
  if (t < RELd) {
    float bv = b6[t];
    float acc[4] = {bv, bv, bv, bv};
    const float4* w6a = (const float4*)(W6 + (size_t)t * (2 * RELd));
    const float4* w6b = (const float4*)(W6 + (size_t)t * (2 * RELd) + RELd);
    for (int k = 0; k < RELd / 4; ++k) {
      float4 wa = w6a[k], wb = w6b[k];
#pragma unroll
      for (int s = 0; s < 4; ++s)
        acc[s] += dot4(wa, ((const float4*)al[s])[k]) +
                  dot4(wb, ((const float4*)be[s])[k]);
    }
#pragma unroll
    for (int s = 0; s < 4; ++s) V_A[(size_t)(b0 + s) * RELd + t] = acc[s];
  }
}

// ---------------------------------------------------------------------------
// attvec = Watt . cat(X2, V_A) + batt   4 batch rows/block, grid 128
// ---------------------------------------------------------------------------
__global__ __launch_bounds__(256) void attvec_kernel(
    const float* __restrict__ X2, const float* __restrict__ V_A,
    const float* __restrict__ Watt, const float* __restrict__ batt,
    float* __restrict__ attv) {
  int b0 = blockIdx.x * 4;
  int t = threadIdx.x;
  __shared__ float cv[4][ADIMd + RELd];  // [4][600]
  for (int i = t; i < 4 * 600; i += 256) {
    int s = i / 600, k = i % 600;
    cv[s][k] = (k < ADIMd) ? X2[(size_t)(b0 + s) * ADIMd + k]
                           : V_A[(size_t)(b0 + s) * RELd + (k - ADIMd)];
  }
  __syncthreads();
  if (t < RELd) {
    float bv = batt[t];
    float acc[4] = {bv, bv, bv, bv};
    const float4* w = (const float4*)(Watt + (size_t)t * 600);
    for (int k = 0; k < 150; ++k) {
      float4 wv = w[k];
#pragma unroll
      for (int s = 0; s < 4; ++s) acc[s] += dot4(wv, ((const float4*)cv[s])[k]);
    }
#pragma unroll
    for (int s = 0; s < 4; ++s) attv[(size_t)(b0 + s) * RELd + t] = acc[s];
  }
}

// ---------------------------------------------------------------------------
// rel_att: softmax over 400 of attv[b] . rel_emb[r]   block per b
// ---------------------------------------------------------------------------
__global__ __launch_bounds__(256) void rel_att_kernel(
    const float* __restrict__ attv, const float* __restrict__ rel_emb,
    float* __restrict__ out_ratt) {
  int b = blockIdx.x;
  int t = threadIdx.x;
  __shared__ float av[RELd];
  __shared__ float wred[4];
  if (t < 50) ((float4*)av)[t] = ((const float4*)(attv + (size_t)b * RELd))[t];
  __syncthreads();
  float l0, l1 = -INFINITY;
  {
    const float4* rp = (const float4*)(rel_emb + (size_t)t * RELd);
    float acc = 0.f;
    for (int k = 0; k < 50; ++k) acc += dot4(rp[k], ((const float4*)av)[k]);
    l0 = acc;
  }
  if (t + 256 < NRr) {
    const float4* rp = (const float4*)(rel_emb + (size_t)(t + 256) * RELd);
    float acc = 0.f;
    for (int k = 0; k < 50; ++k) acc += dot4(rp[k], ((const float4*)av)[k]);
    l1 = acc;
  }
  int w = t >> 6, lane = t & 63;
  float m = wave_rmax(fmaxf(l0, l1));
  if (lane == 0) wred[w] = m;
  __syncthreads();
  m = fmaxf(fmaxf(wred[0], wred[1]), fmaxf(wred[2], wred[3]));
  __syncthreads();
  float e0 = expf(l0 - m);
  float e1 = (t + 256 < NRr) ? expf(l1 - m) : 0.f;
  float s = wave_rsum(e0 + e1);
  if (lane == 0) wred[w] = s;
  __syncthreads();
  s = wred[0] + wred[1] + wred[2] + wred[3];
  float inv = 1.f / s;
  out_ratt[(size_t)b * NRr + t] = e0 * inv;
  if (t + 256 < NRr) out_ratt[(size_t)b * NRr + t + 256] = e1 * inv;
}

// ---------------------------------------------------------------------------
// scores: dist = softmax(A_emb . X2 - (1-mask)*HUGE), entropy. block per b.
// ---------------------------------------------------------------------------
__global__ __launch_bounds__(256) void scores_kernel(
    const float* __restrict__ X2, const float* __restrict__ rel_emb,
    const float* __restrict__ ent_emb, const int* __restrict__ r_space,
    const int* __restrict__ e_space, const float* __restrict__ mask,
    float* __restrict__ out_dist, float* __restrict__ out_ent) {
  int b = blockIdx.x;
  int t = threadIdx.x;
  __shared__ float x2s[ADIMd];
  __shared__ float wred[4];
  if (t < 100) ((float4*)x2s)[t] = ((const float4*)(X2 + (size_t)b * ADIMd))[t];
  __syncthreads();
  int r = r_space[(size_t)b * AA + t];
  int ei = e_space[(size_t)b * AA + t];
  const float4* rp = (const float4*)(rel_emb + (size_t)r * RELd);
  const float4* ep = (const float4*)(ent_emb + (size_t)ei * ENTd);
  float acc = 0.f;
  for (int k = 0; k < 50; ++k) acc += dot4(rp[k], ((const float4*)x2s)[k]);
  for (int k = 0; k < 50; ++k) acc += dot4(ep[k], ((const float4*)x2s)[50 + k]);
  float score = acc - (1.f - mask[(size_t)b * AA + t]) * 1e31f;
  int w = t >> 6, lane = t & 63;
  float m = wave_rmax(score);
  if (lane == 0) wred[w] = m;
  __syncthreads();
  m = fmaxf(fmaxf(wred[0], wred[1]), fmaxf(wred[2], wred[3]));
  __syncthreads();
  float e = expf(score - m);
  float s = wave_rsum(e);
  if (lane == 0) wred[w] = s;
  __syncthreads();
  s = wred[0] + wred[1] + wred[2] + wred[3];
  float p = e / s;
  out_dist[(size_t)b * AA + t] = p;
  float ent = -p * logf(p + 1e-20f);
  float es = wave_rsum(ent);
  __syncthreads();
  if (lane == 0) wred[w] = es;
  __syncthreads();
  if (t == 0) out_ent[b] = wred[0] + wred[1] + wred[2] + wred[3];
}

// ---------------------------------------------------------------------------
extern "C" void kernel_launch(void* const* d_in, const int* in_sizes, int n_in,
                              void* d_out, int out_size, void* d_ws,
                              size_t ws_size, hipStream_t stream) {
  const float* H = (const float*)d_in[0];
  const float* mask = (const float*)d_in[1];
  const float* ent_emb = (const float*)d_in[2];
  const float* rel_emb = (const float*)d_in[3];
  const float* W1 = (const float*)d_in[4];
  const float* b1 = (const float*)d_in[5];
  const float* W2 = (const float*)d_in[6];
  const float* b2 = (const float*)d_in[7];
  const float* W3 = (const float*)d_in[8];
  const float* b3 = (const float*)d_in[9];
  const float* W4 = (const float*)d_in[10];
  const float* b4 = (const float*)d_in[11];
  const float* W5 = (const float*)d_in[12];
  const float* b5 = (const float*)d_in[13];
  const float* W6 = (const float*)d_in[14];
  const float* b6 = (const float*)d_in[15];
  const float* Watt = (const float*)d_in[16];
  const float* batt = (const float*)d_in[17];
  const int* e_idx = (const int*)d_in[18];
  const int* q_idx = (const int*)d_in[19];
  const int* pred_id = (const int*)d_in[20];
  const int* r_space = (const int*)d_in[21];
  const int* e_space = (const int*)d_in[22];

  float* ws = (float*)d_ws;
  float* RK = ws;                    // 400*200   = 80000
  float* alpha_base = ws + 80000;    // 200 (pad to 256)
  float* X = ws + 80256;             // 512*400   = 204800
  float* X2 = ws + 285056;           // 512*400   = 204800
  float* V_A = ws + 489856;          // 512*200   = 102400
  float* attv = ws + 592256;         // 512*200   = 102400

  float* out = (float*)d_out;
  float* out_dist = out;                    // [512,256]
  float* out_ent = out + BB * AA;           // [512]
  float* out_ratt = out + BB * AA + BB;     // [512,400]

  hipLaunchKernelGGL(prep_kernel, dim3(51), dim3(256), 0, stream, rel_emb, W4,
                     b4, W5, b5, RK, alpha_base);
  hipLaunchKernelGGL(x1_kernel, dim3(128, 2), dim3(256), 0, stream, ent_emb,
                     rel_emb, H, e_idx, q_idx, W1, b1, X);
  hipLaunchKernelGGL(x2_kernel, dim3(128, 2), dim3(256), 0, stream, X, W2, b2,
                     X2);
  hipLaunchKernelGGL(pred_path_kernel, dim3(128), dim3(256), 0, stream,
                     ent_emb, rel_emb, pred_id, W3, b3, W5, alpha_base, W6, b6,
                     RK, V_A);
  hipLaunchKernelGGL(attvec_kernel, dim3(128), dim3(256), 0, stream, X2, V_A,
                     Watt, batt, attv);
  hipLaunchKernelGGL(rel_att_kernel, dim3(512), dim3(256), 0, stream, attv,
                     rel_emb, out_ratt);
  hipLaunchKernelGGL(scores_kernel, dim3(512), dim3(256), 0, stream, X2,
                     rel_emb, ent_emb, r_space, e_space, mask, out_dist,
                     out_ent);
}

// Round 2
// 179.225 us; speedup vs baseline: 1.2942x; 1.2942x over previous
//
#include <hip/hip_runtime.h>
#include <cstdint>
#include <cstddef>

#define BB 512
#define NEn 100000
#define NRr 400
#define AA 256
#define ENTd 200
#define RELd 200
#define HISTd 400
#define ADIMd 400

__device__ __forceinline__ float dot4(const float4 a, const float4 b) {
  return a.x * b.x + a.y * b.y + a.z * b.z + a.w * b.w;
}
__device__ __forceinline__ float wave_rmax(float v) {
#pragma unroll
  for (int off = 32; off > 0; off >>= 1) v = fmaxf(v, __shfl_xor(v, off));
  return v;
}
__device__ __forceinline__ float wave_rsum(float v) {
#pragma unroll
  for (int off = 32; off > 0; off >>= 1) v += __shfl_xor(v, off);
  return v;
}

// ---------------------------------------------------------------------------
// prep1: batch-invariant stage 1.
//  blk 0        : rel_sum -> ab = W5l.rel_sum + b5           [200]
//  blk 1..50    : RK = W4.rel + b4                           [400,200] (8 rows)
//  blk 51..75   : P = 400 * W6a . W5r                        [200,200] (8 rows)
//  blk 76..100  : W6bb = Watt_b . W6b                        [200,200] (8 rows)
// ---------------------------------------------------------------------------
__global__ __launch_bounds__(256) void prep1_kernel(
    const float* __restrict__ rel_emb, const float* __restrict__ W4,
    const float* __restrict__ b4, const float* __restrict__ W5,
    const float* __restrict__ b5, const float* __restrict__ W6,
    const float* __restrict__ Watt, float* __restrict__ RK,
    float* __restrict__ P, float* __restrict__ W6bb, float* __restrict__ ab) {
  int t = threadIdx.x;
  int blk = blockIdx.x;
  if (blk == 0) {
    __shared__ float rs[RELd];
    if (t < RELd) {
      float s = 0.f;
      for (int r = 0; r < NRr; ++r) s += rel_emb[(size_t)r * RELd + t];
      rs[t] = s;
    }
    __syncthreads();
    if (t < RELd) {
      float acc = b5[t];
      const float4* w = (const float4*)(W5 + (size_t)t * 400);
      for (int k = 0; k < 50; ++k) acc += dot4(w[k], ((const float4*)rs)[k]);
      ab[t] = acc;
    }
  } else if (blk <= 50) {
    int r0 = (blk - 1) * 8;
    __shared__ float re[8][RELd];
    for (int i = t; i < 8 * RELd; i += 256)
      re[i / RELd][i % RELd] = rel_emb[(size_t)(r0 + i / RELd) * RELd + i % RELd];
    __syncthreads();
    if (t < RELd) {
      float bv = b4[t];
      float acc[8];
#pragma unroll
      for (int s = 0; s < 8; ++s) acc[s] = bv;
      const float4* w = (const float4*)(W4 + (size_t)t * RELd);
      for (int k = 0; k < RELd / 4; ++k) {
        float4 wv = w[k];
#pragma unroll
        for (int s = 0; s < 8; ++s) acc[s] += dot4(wv, ((const float4*)re[s])[k]);
      }
#pragma unroll
      for (int s = 0; s < 8; ++s) RK[(size_t)(r0 + s) * RELd + t] = acc[s];
    }
  } else if (blk <= 75) {
    int i0 = (blk - 51) * 8;
    __shared__ float w6s[8][200];
    for (int i = t; i < 8 * 200; i += 256)
      w6s[i / 200][i % 200] = W6[(size_t)(i0 + i / 200) * 400 + i % 200];
    __syncthreads();
    if (t < 200) {
      int k = t;
      float acc[8] = {0, 0, 0, 0, 0, 0, 0, 0};
      for (int j = 0; j < 200; ++j) {
        float rd = W5[(size_t)j * 400 + 200 + k];
#pragma unroll
        for (int s = 0; s < 8; ++s) acc[s] += w6s[s][j] * rd;
      }
#pragma unroll
      for (int s = 0; s < 8; ++s) P[(size_t)(i0 + s) * 200 + k] = 400.f * acc[s];
    }
  } else {
    int u0 = (blk - 76) * 8;
    __shared__ float wbs[8][200];
    for (int i = t; i < 8 * 200; i += 256)
      wbs[i / 200][i % 200] = Watt[(size_t)(u0 + i / 200) * 600 + 400 + i % 200];
    __syncthreads();
    if (t < 200) {
      int j = t;
      float acc[8] = {0, 0, 0, 0, 0, 0, 0, 0};
      for (int i = 0; i < 200; ++i) {
        float rd = W6[(size_t)i * 400 + 200 + j];
#pragma unroll
        for (int s = 0; s < 8; ++s) acc[s] += wbs[s][i] * rd;
      }
#pragma unroll
      for (int s = 0; s < 8; ++s) W6bb[(size_t)(u0 + s) * 200 + j] = acc[s];
    }
  }
}

// ---------------------------------------------------------------------------
// prep2: batch-invariant stage 2 (needs prep1 outputs).
//  blk 0..49   : S_r = W3^T . RK_r  [400,200] ; c_r = b3.RK_r (8 rows)
//  blk 50..74  : Q = Watt_b . P     [200,200] (8 rows)
//  blk 75..124 : REatt_r = rel_r . W6bb^T  [400,200] (8 rows)
//  blk 125     : v1 = batt + Watt_b.(b6 + W6a.ab)
// ---------------------------------------------------------------------------
__global__ __launch_bounds__(256) void prep2_kernel(
    const float* __restrict__ rel_emb, const float* __restrict__ W3,
    const float* __restrict__ b3, const float* __restrict__ W6,
    const float* __restrict__ Watt, const float* __restrict__ batt,
    const float* __restrict__ b6, const float* __restrict__ RK,
    const float* __restrict__ P, const float* __restrict__ W6bb,
    const float* __restrict__ ab, float* __restrict__ S,
    float* __restrict__ cvec, float* __restrict__ Q,
    float* __restrict__ REatt, float* __restrict__ v1) {
  int t = threadIdx.x;
  int blk = blockIdx.x;
  if (blk < 50) {
    int r0 = blk * 8;
    __shared__ float rks[8][200];
    __shared__ float b3s[200];
    for (int i = t; i < 8 * 200; i += 256)
      rks[i / 200][i % 200] = RK[(size_t)(r0 + i / 200) * 200 + i % 200];
    if (t < 200) b3s[t] = b3[t];
    __syncthreads();
    if (t < 200) {
      int i = t;
      float acc[8] = {0, 0, 0, 0, 0, 0, 0, 0};
      for (int j = 0; j < 200; ++j) {
        float w3v = W3[(size_t)j * 200 + i];
#pragma unroll
        for (int s = 0; s < 8; ++s) acc[s] += w3v * rks[s][j];
      }
#pragma unroll
      for (int s = 0; s < 8; ++s) S[(size_t)(r0 + s) * 200 + i] = acc[s];
    }
    {
      int w = t >> 6, lane = t & 63;
      float p0 = 0.f, p1 = 0.f;
      for (int j = lane; j < 200; j += 64) {
        p0 += b3s[j] * rks[w][j];
        p1 += b3s[j] * rks[w + 4][j];
      }
      p0 = wave_rsum(p0);
      p1 = wave_rsum(p1);
      if (lane == 0) {
        cvec[r0 + w] = p0;
        cvec[r0 + w + 4] = p1;
      }
    }
  } else if (blk < 75) {
    int u0 = (blk - 50) * 8;
    __shared__ float wbs[8][200];
    for (int i = t; i < 8 * 200; i += 256)
      wbs[i / 200][i % 200] = Watt[(size_t)(u0 + i / 200) * 600 + 400 + i % 200];
    __syncthreads();
    if (t < 200) {
      int k = t;
      float acc[8] = {0, 0, 0, 0, 0, 0, 0, 0};
      for (int i = 0; i < 200; ++i) {
        float rd = P[(size_t)i * 200 + k];
#pragma unroll
        for (int s = 0; s < 8; ++s) acc[s] += wbs[s][i] * rd;
      }
#pragma unroll
      for (int s = 0; s < 8; ++s) Q[(size_t)(u0 + s) * 200 + k] = acc[s];
    }
  } else if (blk < 125) {
    int r0 = (blk - 75) * 8;
    __shared__ float rels[8][200];
    for (int i = t; i < 8 * 200; i += 256)
      rels[i / 200][i % 200] = rel_emb[(size_t)(r0 + i / 200) * 200 + i % 200];
    __syncthreads();
    if (t < 200) {
      float acc[8] = {0, 0, 0, 0, 0, 0, 0, 0};
      const float4* w = (const float4*)(W6bb + (size_t)t * 200);
      for (int k = 0; k < 50; ++k) {
        float4 wv = w[k];
#pragma unroll
        for (int s = 0; s < 8; ++s) acc[s] += dot4(wv, ((const float4*)rels[s])[k]);
      }
#pragma unroll
      for (int s = 0; s < 8; ++s) REatt[(size_t)(r0 + s) * 200 + t] = acc[s];
    }
  } else {
    __shared__ float abs_[200];
    __shared__ float us[200];
    if (t < 200) abs_[t] = ab[t];
    __syncthreads();
    if (t < 200) {
      float u = b6[t];
      const float4* w = (const float4*)(W6 + (size_t)t * 400);
      for (int k = 0; k < 50; ++k) u += dot4(w[k], ((const float4*)abs_)[k]);
      us[t] = u;
    }
    __syncthreads();
    if (t < 200) {
      float v = batt[t];
      const float4* w = (const float4*)(Watt + (size_t)t * 600 + 400);
      for (int k = 0; k < 50; ++k) v += dot4(w[k], ((const float4*)us)[k]);
      v1[t] = v;
    }
  }
}

// ---------------------------------------------------------------------------
// x1: X = relu(W1 . cat(E,H,Q) + b1)   tile: 4 batch rows x 200 outputs
// ---------------------------------------------------------------------------
__global__ __launch_bounds__(256) void x1_kernel(
    const float* __restrict__ ent_emb, const float* __restrict__ rel_emb,
    const float* __restrict__ H, const int* __restrict__ e_idx,
    const int* __restrict__ q_idx, const float* __restrict__ W1,
    const float* __restrict__ b1, float* __restrict__ X) {
  int b0 = blockIdx.x * 4;
  int t = threadIdx.x;
  __shared__ float cv[4][ENTd + HISTd + RELd];  // [4][800]
  for (int i = t; i < 4 * 800; i += 256) {
    int s = i / 800, k = i % 800;
    float v;
    if (k < ENTd)
      v = ent_emb[(size_t)e_idx[b0 + s] * ENTd + k];
    else if (k < ENTd + HISTd)
      v = H[(size_t)(b0 + s) * HISTd + (k - ENTd)];
    else
      v = rel_emb[(size_t)q_idx[b0 + s] * RELd + (k - ENTd - HISTd)];
    cv[s][k] = v;
  }
  __syncthreads();
  if (t < 200) {
    int j = blockIdx.y * 200 + t;
    float bv = b1[j];
    float acc[4] = {bv, bv, bv, bv};
    const float4* w = (const float4*)(W1 + (size_t)j * 800);
    for (int k = 0; k < 200; ++k) {
      float4 wv = w[k];
#pragma unroll
      for (int s = 0; s < 4; ++s) acc[s] += dot4(wv, ((const float4*)cv[s])[k]);
    }
#pragma unroll
    for (int s = 0; s < 4; ++s)
      X[(size_t)(b0 + s) * ADIMd + j] = fmaxf(acc[s], 0.f);
  }
}

// ---------------------------------------------------------------------------
// x2: X2 = W2 . X + b2
// ---------------------------------------------------------------------------
__global__ __launch_bounds__(256) void x2_kernel(
    const float* __restrict__ X, const float* __restrict__ W2,
    const float* __restrict__ b2, float* __restrict__ X2) {
  int b0 = blockIdx.x * 4;
  int t = threadIdx.x;
  __shared__ float cv[4][ADIMd];
  for (int i = t; i < 4 * ADIMd; i += 256)
    cv[i / ADIMd][i % ADIMd] = X[(size_t)b0 * ADIMd + i];
  __syncthreads();
  if (t < 200) {
    int j = blockIdx.y * 200 + t;
    float bv = b2[j];
    float acc[4] = {bv, bv, bv, bv};
    const float4* w = (const float4*)(W2 + (size_t)j * ADIMd);
    for (int k = 0; k < ADIMd / 4; ++k) {
      float4 wv = w[k];
#pragma unroll
      for (int s = 0; s < 4; ++s) acc[s] += dot4(wv, ((const float4*)cv[s])[k]);
    }
#pragma unroll
    for (int s = 0; s < 4; ++s) X2[(size_t)(b0 + s) * ADIMd + j] = acc[s];
  }
}

// ---------------------------------------------------------------------------
// fused_mid: per 2 batch rows (512 threads):
//   la = pe.S^T + c ; p = softmax(la) ;
//   attv = Watt_a.X2 + Q.pe + p.REatt + v1 ;
//   ratt = softmax(attv . rel^T)   -> written to out
// ---------------------------------------------------------------------------
__global__ __launch_bounds__(512) void fused_mid_kernel(
    const float* __restrict__ ent_emb, const float* __restrict__ rel_emb,
    const int* __restrict__ pred_id, const float* __restrict__ X2,
    const float* __restrict__ S, const float* __restrict__ cvec,
    const float* __restrict__ Q, const float* __restrict__ REatt,
    const float* __restrict__ v1, const float* __restrict__ Watt,
    float* __restrict__ out_ratt) {
  int b0 = blockIdx.x * 2;
  int t = threadIdx.x;
  __shared__ float pe[2][200];
  __shared__ float x2s[2][400];
  __shared__ float pp[2][400];
  __shared__ float av[2][200];
  __shared__ float wred[2][4];
  if (t < 400) {
    int s = t / 200, k = t % 200;
    pe[s][k] = ent_emb[(size_t)pred_id[b0 + s] * ENTd + k];
  }
  for (int i = t; i < 800; i += 512) x2s[i / 400][i % 400] = X2[(size_t)b0 * 400 + i];
  __syncthreads();
  // la
  if (t < 400) {
    float a0 = cvec[t], a1 = a0;
    const float4* sp = (const float4*)(S + (size_t)t * 200);
    for (int k = 0; k < 50; ++k) {
      float4 sv = sp[k];
      a0 += dot4(sv, ((const float4*)pe[0])[k]);
      a1 += dot4(sv, ((const float4*)pe[1])[k]);
    }
    pp[0][t] = a0;
    pp[1][t] = a1;
  }
  __syncthreads();
  int w = t >> 6, lane = t & 63, s = w >> 2, wq = w & 3;
  // softmax(pp rows)
  {
    float m = -INFINITY;
    for (int r = wq * 64 + lane; r < 400; r += 256) m = fmaxf(m, pp[s][r]);
    m = wave_rmax(m);
    if (lane == 0) wred[s][wq] = m;
    __syncthreads();
    m = fmaxf(fmaxf(wred[s][0], wred[s][1]), fmaxf(wred[s][2], wred[s][3]));
    __syncthreads();
    float sum = 0.f;
    for (int r = wq * 64 + lane; r < 400; r += 256) {
      float e = expf(pp[s][r] - m);
      pp[s][r] = e;
      sum += e;
    }
    sum = wave_rsum(sum);
    if (lane == 0) wred[s][wq] = sum;
    __syncthreads();
    sum = wred[s][0] + wred[s][1] + wred[s][2] + wred[s][3];
    float inv = 1.f / sum;
    for (int r = wq * 64 + lane; r < 400; r += 256) pp[s][r] *= inv;
  }
  __syncthreads();
  // attv
  if (t < 400) {
    int s2 = t / 200, j = t % 200;
    float a = v1[j];
    const float4* wp = (const float4*)(Watt + (size_t)j * 600);
    for (int k = 0; k < 100; ++k) a += dot4(wp[k], ((const float4*)x2s[s2])[k]);
    const float4* qp = (const float4*)(Q + (size_t)j * 200);
    for (int k = 0; k < 50; ++k) a += dot4(qp[k], ((const float4*)pe[s2])[k]);
    for (int r = 0; r < 400; ++r) a += pp[s2][r] * REatt[(size_t)r * 200 + j];
    av[s2][j] = a;
  }
  __syncthreads();
  // logits into pp (reuse)
  if (t < 400) {
    const float4* rp = (const float4*)(rel_emb + (size_t)t * 200);
    float l0 = 0.f, l1 = 0.f;
    for (int k = 0; k < 50; ++k) {
      float4 rv = rp[k];
      l0 += dot4(rv, ((const float4*)av[0])[k]);
      l1 += dot4(rv, ((const float4*)av[1])[k]);
    }
    pp[0][t] = l0;
    pp[1][t] = l1;
  }
  __syncthreads();
  // softmax + write
  {
    float m = -INFINITY;
    for (int r = wq * 64 + lane; r < 400; r += 256) m = fmaxf(m, pp[s][r]);
    m = wave_rmax(m);
    if (lane == 0) wred[s][wq] = m;
    __syncthreads();
    m = fmaxf(fmaxf(wred[s][0], wred[s][1]), fmaxf(wred[s][2], wred[s][3]));
    __syncthreads();
    float sum = 0.f;
    for (int r = wq * 64 + lane; r < 400; r += 256) {
      float e = expf(pp[s][r] - m);
      pp[s][r] = e;
      sum += e;
    }
    sum = wave_rsum(sum);
    if (lane == 0) wred[s][wq] = sum;
    __syncthreads();
    sum = wred[s][0] + wred[s][1] + wred[s][2] + wred[s][3];
    float inv = 1.f / sum;
    for (int r = wq * 64 + lane; r < 400; r += 256)
      out_ratt[(size_t)(b0 + s) * 400 + r] = pp[s][r] * inv;
  }
}

// ---------------------------------------------------------------------------
// scores: dist = softmax(A_emb . X2 - (1-mask)*HUGE), entropy. block per b.
// ---------------------------------------------------------------------------
__global__ __launch_bounds__(256) void scores_kernel(
    const float* __restrict__ X2, const float* __restrict__ rel_emb,
    const float* __restrict__ ent_emb, const int* __restrict__ r_space,
    const int* __restrict__ e_space, const float* __restrict__ mask,
    float* __restrict__ out_dist, float* __restrict__ out_ent) {
  int b = blockIdx.x;
  int t = threadIdx.x;
  __shared__ float x2s[ADIMd];
  __shared__ float wred[4];
  if (t < 100) ((float4*)x2s)[t] = ((const float4*)(X2 + (size_t)b * ADIMd))[t];
  __syncthreads();
  int r = r_space[(size_t)b * AA + t];
  int ei = e_space[(size_t)b * AA + t];
  const float4* rp = (const float4*)(rel_emb + (size_t)r * RELd);
  const float4* ep = (const float4*)(ent_emb + (size_t)ei * ENTd);
  float acc = 0.f;
  for (int k = 0; k < 50; ++k) acc += dot4(rp[k], ((const float4*)x2s)[k]);
  for (int k = 0; k < 50; ++k) acc += dot4(ep[k], ((const float4*)x2s)[50 + k]);
  float score = acc - (1.f - mask[(size_t)b * AA + t]) * 1e31f;
  int w = t >> 6, lane = t & 63;
  float m = wave_rmax(score);
  if (lane == 0) wred[w] = m;
  __syncthreads();
  m = fmaxf(fmaxf(wred[0], wred[1]), fmaxf(wred[2], wred[3]));
  __syncthreads();
  float e = expf(score - m);
  float sm = wave_rsum(e);
  if (lane == 0) wred[w] = sm;
  __syncthreads();
  sm = wred[0] + wred[1] + wred[2] + wred[3];
  float p = e / sm;
  out_dist[(size_t)b * AA + t] = p;
  float ent = -p * logf(p + 1e-20f);
  float es = wave_rsum(ent);
  __syncthreads();
  if (lane == 0) wred[w] = es;
  __syncthreads();
  if (t == 0) out_ent[b] = wred[0] + wred[1] + wred[2] + wred[3];
}

// ---------------------------------------------------------------------------
extern "C" void kernel_launch(void* const* d_in, const int* in_sizes, int n_in,
                              void* d_out, int out_size, void* d_ws,
                              size_t ws_size, hipStream_t stream) {
  const float* H = (const float*)d_in[0];
  const float* mask = (const float*)d_in[1];
  const float* ent_emb = (const float*)d_in[2];
  const float* rel_emb = (const float*)d_in[3];
  const float* W1 = (const float*)d_in[4];
  const float* b1 = (const float*)d_in[5];
  const float* W2 = (const float*)d_in[6];
  const float* b2 = (const float*)d_in[7];
  const float* W3 = (const float*)d_in[8];
  const float* b3 = (const float*)d_in[9];
  const float* W4 = (const float*)d_in[10];
  const float* b4 = (const float*)d_in[11];
  const float* W5 = (const float*)d_in[12];
  const float* b5 = (const float*)d_in[13];
  const float* W6 = (const float*)d_in[14];
  const float* b6 = (const float*)d_in[15];
  const float* Watt = (const float*)d_in[16];
  const float* batt = (const float*)d_in[17];
  const int* e_idx = (const int*)d_in[18];
  const int* q_idx = (const int*)d_in[19];
  const int* pred_id = (const int*)d_in[20];
  const int* r_space = (const int*)d_in[21];
  const int* e_space = (const int*)d_in[22];

  float* ws = (float*)d_ws;
  float* RK = ws;                  // 80000
  float* S = ws + 80000;           // 80000
  float* cvec = ws + 160000;       // 512
  float* P = ws + 160512;          // 40000
  float* Q = ws + 200512;          // 40000
  float* W6bb = ws + 240512;       // 40000
  float* REatt = ws + 280512;      // 80000
  float* ab = ws + 360512;         // 256
  float* v1 = ws + 360768;         // 256
  float* X = ws + 361024;          // 204800
  float* X2 = ws + 565824;         // 204800  (end 770624 floats ~= 3.1 MB)

  float* out = (float*)d_out;
  float* out_dist = out;                 // [512,256]
  float* out_ent = out + BB * AA;        // [512]
  float* out_ratt = out + BB * AA + BB;  // [512,400]

  hipLaunchKernelGGL(prep1_kernel, dim3(101), dim3(256), 0, stream, rel_emb,
                     W4, b4, W5, b5, W6, Watt, RK, P, W6bb, ab);
  hipLaunchKernelGGL(prep2_kernel, dim3(126), dim3(256), 0, stream, rel_emb,
                     W3, b3, W6, Watt, batt, b6, RK, P, W6bb, ab, S, cvec, Q,
                     REatt, v1);
  hipLaunchKernelGGL(x1_kernel, dim3(128, 2), dim3(256), 0, stream, ent_emb,
                     rel_emb, H, e_idx, q_idx, W1, b1, X);
  hipLaunchKernelGGL(x2_kernel, dim3(128, 2), dim3(256), 0, stream, X, W2, b2,
                     X2);
  hipLaunchKernelGGL(fused_mid_kernel, dim3(256), dim3(512), 0, stream,
                     ent_emb, rel_emb, pred_id, X2, S, cvec, Q, REatt, v1,
                     Watt, out_ratt);
  hipLaunchKernelGGL(scores_kernel, dim3(512), dim3(256), 0, stream, X2,
                     rel_emb, ent_emb, r_space, e_space, mask, out_dist,
                     out_ent);
}